// Round 17
// baseline (127.902 us; speedup 1.0000x reference)
//
#include <hip/hip_runtime.h>
#include <stdint.h>

// DCNv2 forward, MI355X — R28: 16 waves (4/SIMD) in fused_gemm.
//  R27 post-mortem: the ~44us fillBufferAligned re-poison is harness-fixed;
//  controllable = fused(51.5) + K0(~20) + gaps. Fused steady = 3000cy/period
//  vs ~1000cy modeled work; waits are period-old, conflicts fixed, gather
//  lines coalesced => ~2000cy of UNATTRIBUTED latency. Generic fix: double
//  TLP (2 -> 4 waves/SIMD). Same block geometry (BM=64, grid 256, LDS
//  100KB, 1 block/CU), 1024 threads: wave owns 16 cols (1 B-frag/k-tile,
//  2 GLOAD16/period), sampler granule 4ch (4 GLOAD8/period; same bytes,
//  same coalesced line count). Ledger: enter 6 [B(P)2,G(P+1)4], +6 issues,
//  vmcnt(10)->MFMA, vmcnt(6)->bilin, leave 6. Tail vmcnt(6)/(2)/(0).
//  Offset-conv prologue: waves 0-7 only (code unchanged). K0 = R27.

#define CIN 256
#define COUT 256
#define HWS 4096      // H*W
#define MTOT 16384    // B*H*W
#define KTOT 2304     // CIN*9
#define SPLITK 8

typedef __attribute__((ext_vector_type(8))) short bf16x8;
typedef __attribute__((ext_vector_type(4))) float f32x4;

__device__ __forceinline__ unsigned short f2bf(float f) {
  unsigned int u = __float_as_uint(f);
  unsigned int r = (u + 0x7fffu + ((u >> 16) & 1u)) >> 16;
  return (unsigned short)r;
}
__device__ __forceinline__ float bf2f(unsigned short u) {
  return __uint_as_float(((unsigned int)u) << 16);
}
// bf16 pair unpack: 1 VALU each.
__device__ __forceinline__ float bflo(unsigned int u) { return __uint_as_float(u << 16); }
__device__ __forceinline__ float bfhi(unsigned int u) { return __uint_as_float(u & 0xffff0000u); }

__device__ __forceinline__ void gload_lds16(const void* g, void* l) {
  __builtin_amdgcn_global_load_lds((const __attribute__((address_space(1))) void*)g,
                                   (__attribute__((address_space(3))) void*)l, 16, 0, 0);
}

// Issue-pinned loads; completion via manual counted s_waitcnt + sched fence.
#define GLOAD16(D, P) asm volatile("global_load_dwordx4 %0, %1, off" : "=v"(D) : "v"(P))
#define GLOAD8(D, P)  asm volatile("global_load_dwordx2 %0, %1, off" : "=v"(D) : "v"(P))
#define WAITVM(N)                                            \
  {                                                          \
    asm volatile("s_waitcnt vmcnt(" #N ")" ::: "memory");    \
    __builtin_amdgcn_sched_barrier(0);                       \
  }
#define BARRIER_LGKM                                                  \
  { asm volatile("s_waitcnt lgkmcnt(0)\n\ts_barrier" ::: "memory"); }

// As column swizzle: applied identically on write and read (bits 3..5 only).
#define ASW(c, rr) ((c) ^ (((rr) & 7) << 3))

// ---------------- K0: fused transpose (64x64 tiles) + weight prep ----------------
__global__ __launch_bounds__(256) void prep_and_transpose(const float* __restrict__ x,
                                                          const float* __restrict__ w,
                                                          const float* __restrict__ pw,
                                                          unsigned short* __restrict__ xt,
                                                          unsigned short* __restrict__ WB,
                                                          unsigned short* __restrict__ PWs) {
  __shared__ float tile[64][65];   // 16,640 B
  int bid = blockIdx.x;
  int tid = threadIdx.x;
  if (bid < 1024) {
    int b = bid >> 8;
    int rest = bid & 255;
    int hw0 = (rest & 63) * 64;
    int c0 = (rest >> 6) * 64;
    {
      int col4 = (tid & 15) * 4;
      int crow = tid >> 4;
#pragma unroll
      for (int it = 0; it < 4; ++it) {
        int c = it * 16 + crow;
        float4 v = *(const float4*)&x[(size_t)(b * CIN + c0 + c) * HWS + hw0 + col4];
        tile[c][col4] = v.x;
        tile[c][col4 + 1] = v.y;
        tile[c][col4 + 2] = v.z;
        tile[c][col4 + 3] = v.w;
      }
    }
    __syncthreads();
    {
      int cc0 = (tid & 7) * 8;
      int rrow = tid >> 3;
#pragma unroll
      for (int it = 0; it < 2; ++it) {
        int r = it * 32 + rrow;
        uint4 o;
        o.x = (unsigned)f2bf(tile[cc0][r])     | ((unsigned)f2bf(tile[cc0 + 1][r]) << 16);
        o.y = (unsigned)f2bf(tile[cc0 + 2][r]) | ((unsigned)f2bf(tile[cc0 + 3][r]) << 16);
        o.z = (unsigned)f2bf(tile[cc0 + 4][r]) | ((unsigned)f2bf(tile[cc0 + 5][r]) << 16);
        o.w = (unsigned)f2bf(tile[cc0 + 6][r]) | ((unsigned)f2bf(tile[cc0 + 7][r]) << 16);
        *(uint4*)&xt[(size_t)(b * HWS + hw0 + r) * CIN + c0 + cc0] = o;
      }
    }
  } else {
    int idx = (bid - 1024) * 256 + tid;
    if (idx < KTOT * COUT) {
      // WB2[t][j][quad][row][8]: f = (((t*16+j)*4+quad)*16+row)*8+e
      int f = idx;
      int e = f & 7;
      int row = (f >> 3) & 15;
      int quad = (f >> 7) & 3;
      int j = (f >> 9) & 15;
      int t = f >> 13;                 // 0..71
      int kk = t * 32 + quad * 8 + e;
      int o = j * 16 + row;
      int k = kk >> 8, c = kk & 255;
      WB[f] = f2bf(w[o * KTOT + c * 9 + k]);
    } else {
      int f2 = idx - KTOT * COUT;   // < 2304*32
      int t_ = f2 & 7;
      int rest = f2 >> 3;
      int j = rest & 31;
      int kk = (rest >> 5) * 8 + t_;
      int k = kk >> 8, c = kk & 255;
      float v = (j < 27) ? pw[j * KTOT + c * 9 + k] : 0.0f;
      PWs[f2] = f2bf(v);
    }
  }
}

// ---------------- K3: fused offset-conv + index-prep + sample + GEMM ----------------
// 1024 thr / 16 waves, BM=64. Wave wv: 64 rows x 16 cols (n-tile wv).
// Sampler: r = tid>>4 (row), go = (sub>>3)*32 + (sub&7)*4 (4-ch granule,
// sub = tid&15). 36 periods of 2 k-tiles, R22 counted-vmcnt discipline.
__device__ __forceinline__ void bilin4p(const uint2 c00, const uint2 c01,
                                        const uint2 c10, const uint2 c11,
                                        const float4 w4, unsigned short* dst) {
  uint2 o;
  float v0, v1;
  v0 = w4.x * bflo(c00.x) + w4.y * bflo(c01.x) + w4.z * bflo(c10.x) + w4.w * bflo(c11.x);
  v1 = w4.x * bfhi(c00.x) + w4.y * bfhi(c01.x) + w4.z * bfhi(c10.x) + w4.w * bfhi(c11.x);
  o.x = (unsigned)f2bf(v0) | ((unsigned)f2bf(v1) << 16);
  v0 = w4.x * bflo(c00.y) + w4.y * bflo(c01.y) + w4.z * bflo(c10.y) + w4.w * bflo(c11.y);
  v1 = w4.x * bfhi(c00.y) + w4.y * bfhi(c01.y) + w4.z * bfhi(c10.y) + w4.w * bfhi(c11.y);
  o.y = (unsigned)f2bf(v0) | ((unsigned)f2bf(v1) << 16);
  *(uint2*)dst = o;
}

#define MFMA8X(B0, B1)                                                                   \
  acc[0] = __builtin_amdgcn_mfma_f32_16x16x32_bf16(afr0, B0, acc[0], 0, 0, 0);           \
  acc[1] = __builtin_amdgcn_mfma_f32_16x16x32_bf16(afr1, B0, acc[1], 0, 0, 0);           \
  acc[2] = __builtin_amdgcn_mfma_f32_16x16x32_bf16(afr2, B0, acc[2], 0, 0, 0);           \
  acc[3] = __builtin_amdgcn_mfma_f32_16x16x32_bf16(afr3, B0, acc[3], 0, 0, 0);           \
  acc[0] = __builtin_amdgcn_mfma_f32_16x16x32_bf16(afr4, B1, acc[0], 0, 0, 0);           \
  acc[1] = __builtin_amdgcn_mfma_f32_16x16x32_bf16(afr5, B1, acc[1], 0, 0, 0);           \
  acc[2] = __builtin_amdgcn_mfma_f32_16x16x32_bf16(afr6, B1, acc[2], 0, 0, 0);           \
  acc[3] = __builtin_amdgcn_mfma_f32_16x16x32_bf16(afr7, B1, acc[3], 0, 0, 0);

// Steady period P. GI* receive G(P+2 data, GLOAD8); GC* hold G(P+1).
// BI* receive B(P+1) (GLOAD16 x2); BC* hold B(P) (oldest in flight).
#define FITER_P3(P, PAR, GI0, GI1, GI2, GI3, GC0, GC1, GC2, GC3, BC0, BC1, BI0, BI1)     \
  {                                                                                      \
    const unsigned short* btn = bpb + (size_t)(2 * ((P) + 1)) * 8192;                    \
    GLOAD16(BI0, btn);                                                                   \
    GLOAD16(BI1, btn + 8192);                                                            \
    if ((((P) + 2) & 3) == 0) dI4 = Tbl[r][((P) + 2) >> 2][0];                           \
    int cb = ((2 * (P) + 4) & 7) * 32 + go;                                              \
    GLOAD8(GI0, xtb + dI4.x + cb);                                                       \
    GLOAD8(GI1, xtb + dI4.y + cb);                                                       \
    GLOAD8(GI2, xtb + dI4.z + cb);                                                       \
    GLOAD8(GI3, xtb + dI4.w + cb);                                                       \
    afr0 = *(const bf16x8*)&As[PAR][row][ASW(quad * 8, row)];                            \
    afr1 = *(const bf16x8*)&As[PAR][16 + row][ASW(quad * 8, row)];                       \
    afr2 = *(const bf16x8*)&As[PAR][32 + row][ASW(quad * 8, row)];                       \
    afr3 = *(const bf16x8*)&As[PAR][48 + row][ASW(quad * 8, row)];                       \
    afr4 = *(const bf16x8*)&As[PAR][row][ASW(32 + quad * 8, row)];                       \
    afr5 = *(const bf16x8*)&As[PAR][16 + row][ASW(32 + quad * 8, row)];                  \
    afr6 = *(const bf16x8*)&As[PAR][32 + row][ASW(32 + quad * 8, row)];                  \
    afr7 = *(const bf16x8*)&As[PAR][48 + row][ASW(32 + quad * 8, row)];                  \
    if ((((P) + 1) & 3) == 0) dW4 = *(float4*)&Tbl[r][((P) + 1) >> 2][1];                \
    WAITVM(10)                                                                           \
    MFMA8X(BC0, BC1)                                                                     \
    WAITVM(6)                                                                            \
    bilin4p(GC0, GC1, GC2, GC3, dW4, &As[PAR ^ 1][r][ASW(go, r)]);                       \
    BARRIER_LGKM                                                                         \
  }

__global__ __launch_bounds__(1024, 4) void fused_gemm(const unsigned short* __restrict__ xt,
                                                      const unsigned short* __restrict__ PWs,
                                                      const float* __restrict__ p_bias,
                                                      const unsigned short* __restrict__ WB,
                                                      const float* __restrict__ bias,
                                                      float* __restrict__ out) {
  __shared__ unsigned short As[2][64][64];   // 16,384 B, XOR-swizzled columns
  __shared__ int4 Tbl[64][9][2];             // 18,432 B [r][tap]{dI, dW}
  __shared__ float Ptl[8][64][32];           // 65,536 B offset-conv partials

  int tid = threadIdx.x;
  int lane = tid & 63, wv = tid >> 6;        // 16 waves
  int row = lane & 15, quad = lane >> 4;
  int mt = (blockIdx.x & 7) * 32 + (blockIdx.x >> 3);   // XCD-chunked swizzle
  int mb = mt * 64;
  int b = mb >> 12;
  int hw0 = mb & 4095;
  const unsigned short* xtb = xt + ((size_t)b << 20);

  // ---- (a) offset conv (ex-K1): waves 0..7 cover k-tiles 9wv..9wv+8 ----
  if (wv < 8) {
    f32x4 aco[4][2] = {};
    for (int tt = 0; tt < 9; ++tt) {
      int t = wv * 9 + tt;
      int k = t >> 3, c0 = (t & 7) * 32;
      int dyk = k / 3 - 1, dxk = k % 3 - 1;
      const unsigned short* pb = PWs + (size_t)t * 1024 + (quad * 32 + row) * 8;
      bf16x8 ob0 = *(const bf16x8*)pb;           // j=0
      bf16x8 ob1 = *(const bf16x8*)(pb + 128);   // j=1
#pragma unroll
      for (int rs = 0; rs < 4; ++rs) {
        int hw = hw0 + rs * 16 + row;
        int h = hw >> 6, wq = hw & 63;
        int y = h + dyk, xx = wq + dxk;
        bf16x8 oa = {};
        if (((unsigned)y < 64u) && ((unsigned)xx < 64u))
          oa = *(const bf16x8*)(xtb + (size_t)(((y << 6) + xx) << 8) + c0 + quad * 8);
        aco[rs][0] = __builtin_amdgcn_mfma_f32_16x16x32_bf16(oa, ob0, aco[rs][0], 0, 0, 0);
        aco[rs][1] = __builtin_amdgcn_mfma_f32_16x16x32_bf16(oa, ob1, aco[rs][1], 0, 0, 0);
      }
    }
#pragma unroll
    for (int rs = 0; rs < 4; ++rs)
#pragma unroll
      for (int j = 0; j < 2; ++j)
#pragma unroll
        for (int e = 0; e < 4; ++e)
          Ptl[wv][rs * 16 + quad * 4 + e][j * 16 + row] = aco[rs][j][e];
  }
  __syncthreads();

  // ---- (b) reduce 8 waves' partials into Ptl[0] ----
  for (int i = tid; i < 2048; i += 1024) {
    int lm = i >> 5, n = i & 31;
    float s = Ptl[0][lm][n];
#pragma unroll
    for (int w = 1; w < 8; ++w) s += Ptl[w][lm][n];
    Ptl[0][lm][n] = s;
  }
  __syncthreads();

  // ---- (c) index prep (ex-K2): 576 (row, tap) pairs ----
  for (int pr = tid; pr < 576; pr += 1024) {
    int lm = pr / 9;
    int k = pr - lm * 9;
    int m = mb + lm;

    float dy = p_bias[2 * k] + Ptl[0][lm][2 * k];
    float dx = p_bias[2 * k + 1] + Ptl[0][lm][2 * k + 1];
    float mv = p_bias[18 + k] + Ptl[0][lm][18 + k];
    float mk = 1.0f / (1.0f + __expf(-mv));

    int hw = m & 4095, h = hw >> 6, ww = hw & 63;
    float py = (float)(h - 1 + k / 3) + dy;
    float px = (float)(ww - 1 + k % 3) + dx;
    float y0f = floorf(py), x0f = floorf(px);
    float ay = py - y0f, ax = px - x0f;
    int y0 = (int)y0f, x0 = (int)x0f;

    float w00 = (1.f - ay) * (1.f - ax) * mk;
    float w01 = (1.f - ay) * ax * mk;
    float w10 = ay * (1.f - ax) * mk;
    float w11 = ay * ax * mk;

    float vy0 = ((unsigned)y0 < 64u) ? 1.f : 0.f;
    float vy1 = ((unsigned)(y0 + 1) < 64u) ? 1.f : 0.f;
    float vx0 = ((unsigned)x0 < 64u) ? 1.f : 0.f;
    float vx1 = ((unsigned)(x0 + 1) < 64u) ? 1.f : 0.f;
    w00 *= vy0 * vx0; w01 *= vy0 * vx1; w10 *= vy1 * vx0; w11 *= vy1 * vx1;

    int yc0 = min(max(y0, 0), 63), yc1 = min(max(y0 + 1, 0), 63);
    int xc0 = min(max(x0, 0), 63), xc1 = min(max(x0 + 1, 0), 63);

    Tbl[lm][k][0] = make_int4((yc0 * 64 + xc0) * 256, (yc0 * 64 + xc1) * 256,
                              (yc1 * 64 + xc0) * 256, (yc1 * 64 + xc1) * 256);
    *(float4*)&Tbl[lm][k][1] = make_float4(w00, w01, w10, w11);
  }
  __syncthreads();   // full drain (vmcnt+lgkm) BEFORE any pinned loads

  int sub = tid & 15;
  int r = tid >> 4;                        // sampler row 0..63 (16 thr/row)
  int go = (sub >> 3) * 32 + (sub & 7) * 4;  // ch granule (4 ch, 8 B)

  int4 dI4 = Tbl[r][0][0];
  float4 dW4 = *(float4*)&Tbl[r][0][1];

  const unsigned short* bpb = WB + (size_t)wv * 512 + quad * 128 + row * 8;

  f32x4 acc[4] = {};
  uint2 gA0, gA1, gA2, gA3;            // even-period gather set
  uint2 gB0, gB1, gB2, gB3;            // odd-period gather set
  bf16x8 bA0, bA1;                     // even-period B set
  bf16x8 bB0, bB1;                     // odd-period B set
  bf16x8 afr0, afr1, afr2, afr3, afr4, afr5, afr6, afr7;

  // ---- prologue: sample period 0 via compiler loads; pin B(0), G(1) ----
  {
    uint2 p00 = *(const uint2*)(xtb + dI4.x + go);
    uint2 p01 = *(const uint2*)(xtb + dI4.y + go);
    uint2 p10 = *(const uint2*)(xtb + dI4.z + go);
    uint2 p11 = *(const uint2*)(xtb + dI4.w + go);
    bilin4p(p00, p01, p10, p11, dW4, &As[0][r][ASW(go, r)]);
    // pinned issues, ORDER: B(0) x2 first (oldest), then G(1) x4
    GLOAD16(bA0, bpb);
    GLOAD16(bA1, bpb + 8192);
    int cb1 = 64 + go;   // period 1 = tiles 2,3 (ch 64..127), tap 0
    GLOAD8(gA0, xtb + dI4.x + cb1);
    GLOAD8(gA1, xtb + dI4.y + cb1);
    GLOAD8(gA2, xtb + dI4.z + cb1);
    GLOAD8(gA3, xtb + dI4.w + cb1);
  }
  BARRIER_LGKM   // As[0] visible; 6 pinned loads in flight

  // ---- steady loop: periods 0..33 ----
#pragma unroll 1
  for (int p = 0; p < 34; p += 2) {
    FITER_P3(p,     0, gB0, gB1, gB2, gB3, gA0, gA1, gA2, gA3, bA0, bA1, bB0, bB1)
    FITER_P3(p + 1, 1, gA0, gA1, gA2, gA3, gB0, gB1, gB2, gB3, bB0, bB1, bA0, bA1)
  }

  // ---- peeled P=34 (PAR=0): BC=bA=B(34), GC=gA=G(35); issue B(35)->bB ----
  {
    GLOAD16(bB0, bpb + (size_t)70 * 8192);
    GLOAD16(bB1, bpb + (size_t)71 * 8192);
    afr0 = *(const bf16x8*)&As[0][row][ASW(quad * 8, row)];
    afr1 = *(const bf16x8*)&As[0][16 + row][ASW(quad * 8, row)];
    afr2 = *(const bf16x8*)&As[0][32 + row][ASW(quad * 8, row)];
    afr3 = *(const bf16x8*)&As[0][48 + row][ASW(quad * 8, row)];
    afr4 = *(const bf16x8*)&As[0][row][ASW(32 + quad * 8, row)];
    afr5 = *(const bf16x8*)&As[0][16 + row][ASW(32 + quad * 8, row)];
    afr6 = *(const bf16x8*)&As[0][32 + row][ASW(32 + quad * 8, row)];
    afr7 = *(const bf16x8*)&As[0][48 + row][ASW(32 + quad * 8, row)];
    WAITVM(6)    // drains B(34)
    MFMA8X(bA0, bA1)
    WAITVM(2)    // drains G(35)
    bilin4p(gA0, gA1, gA2, gA3, dW4, &As[1][r][ASW(go, r)]);   // dW4 = tap 8
    BARRIER_LGKM
  }
  // ---- peeled P=35 (PAR=1): BC=bB=B(35); no bilin ----
  {
    afr0 = *(const bf16x8*)&As[1][row][ASW(quad * 8, row)];
    afr1 = *(const bf16x8*)&As[1][16 + row][ASW(quad * 8, row)];
    afr2 = *(const bf16x8*)&As[1][32 + row][ASW(quad * 8, row)];
    afr3 = *(const bf16x8*)&As[1][48 + row][ASW(quad * 8, row)];
    afr4 = *(const bf16x8*)&As[1][row][ASW(32 + quad * 8, row)];
    afr5 = *(const bf16x8*)&As[1][16 + row][ASW(32 + quad * 8, row)];
    afr6 = *(const bf16x8*)&As[1][32 + row][ASW(32 + quad * 8, row)];
    afr7 = *(const bf16x8*)&As[1][48 + row][ASW(32 + quad * 8, row)];
    WAITVM(0)
    MFMA8X(bB0, bB1)
  }

  // ---- epilogue: add bias, store NCHW ----
  {
    int o = wv * 16 + row;
    float bo = bias[o];
#pragma unroll
    for (int mi = 0; mi < 4; ++mi) {
      int hw = hw0 + mi * 16 + quad * 4;
      float4 v;
      v.x = acc[mi][0] + bo;
      v.y = acc[mi][1] + bo;
      v.z = acc[mi][2] + bo;
      v.w = acc[mi][3] + bo;
      *(float4*)(out + (((size_t)(b * COUT + o)) << 12) + hw) = v;
    }
  }
}

// ---------------- launch ----------------
extern "C" void kernel_launch(void* const* d_in, const int* in_sizes, int n_in,
                              void* d_out, int out_size, void* d_ws, size_t ws_size,
                              hipStream_t stream) {
  const float* x        = (const float*)d_in[0];
  const float* weight   = (const float*)d_in[1];
  const float* bias     = (const float*)d_in[2];
  const float* p_weight = (const float*)d_in[3];
  const float* p_bias   = (const float*)d_in[4];
  float* out = (float*)d_out;
  char* ws = (char*)d_ws;

  // workspace layout (bytes); total ~9.7 MB
  const size_t OFF_XT   = 0;                          //  8,388,608  bf16 NHWC x
  const size_t OFF_WB   = OFF_XT + 8388608;           //  1,179,648  bf16 WB2
  const size_t OFF_PW   = OFF_WB + 1179648;           //    147,456  bf16

  unsigned short* xt    = (unsigned short*)(ws + OFF_XT);
  unsigned short* WB    = (unsigned short*)(ws + OFF_WB);
  unsigned short* PWs   = (unsigned short*)(ws + OFF_PW);

  prep_and_transpose<<<1024 + 2592, 256, 0, stream>>>(x, weight, p_weight, xt, WB, PWs);
  fused_gemm<<<256, 1024, 0, stream>>>(xt, PWs, p_bias, WB, bias, out);
}

// Round 18
// 124.731 us; speedup vs baseline: 1.0254x; 1.0254x over previous
//
#include <hip/hip_runtime.h>
#include <stdint.h>

// DCNv2 forward, MI355X — R29: R27 (verified best, 123.7us) + T5 s_setprio
//  around the MFMA cluster.
//  R28 post-mortem: 16 waves REGRESSED (fused 51.5->56.4) — the ~2000cy/
//  period unattributed cost is not hideable latency; 8-wave R27 is a strong
//  local optimum (more waves x, fewer waves x, fewer barriers x, no
//  barriers x). Last counter-backed lever: T5 setprio — measured +21-39%
//  ONLY on counted-vmcnt phase-split schedules (m218b/m224; null on
//  lockstep). Our steady loop IS phase-split: waves diverge into
//  {load-issuing, MFMA-entering} roles between lgkm-only barriers.
//  Change: setprio(1)/setprio(0) around MFMA16P in the steady body and
//  both peeled periods. Everything else byte-identical to R27.
//  Pre-committed read: delta within +-1.5us => structure exhausted,
//  declare roofline next round.

#define CIN 256
#define COUT 256
#define HWS 4096      // H*W
#define MTOT 16384    // B*H*W
#define KTOT 2304     // CIN*9
#define SPLITK 8

typedef __attribute__((ext_vector_type(8))) short bf16x8;
typedef __attribute__((ext_vector_type(4))) float f32x4;

__device__ __forceinline__ unsigned short f2bf(float f) {
  unsigned int u = __float_as_uint(f);
  unsigned int r = (u + 0x7fffu + ((u >> 16) & 1u)) >> 16;
  return (unsigned short)r;
}
__device__ __forceinline__ float bf2f(unsigned short u) {
  return __uint_as_float(((unsigned int)u) << 16);
}
// bf16 pair unpack: 1 VALU each.
__device__ __forceinline__ float bflo(unsigned int u) { return __uint_as_float(u << 16); }
__device__ __forceinline__ float bfhi(unsigned int u) { return __uint_as_float(u & 0xffff0000u); }

__device__ __forceinline__ void gload_lds16(const void* g, void* l) {
  __builtin_amdgcn_global_load_lds((const __attribute__((address_space(1))) void*)g,
                                   (__attribute__((address_space(3))) void*)l, 16, 0, 0);
}

// Issue-pinned loads; completion via manual counted s_waitcnt + sched fence.
#define GLOAD16(D, P) asm volatile("global_load_dwordx4 %0, %1, off" : "=v"(D) : "v"(P))
#define WAITVM(N)                                            \
  {                                                          \
    asm volatile("s_waitcnt vmcnt(" #N ")" ::: "memory");    \
    __builtin_amdgcn_sched_barrier(0);                       \
  }
#define BARRIER_LGKM                                                  \
  { asm volatile("s_waitcnt lgkmcnt(0)\n\ts_barrier" ::: "memory"); }

// As column swizzle: applied identically on write and read (bits 3..5 only).
#define ASW(c, rr) ((c) ^ (((rr) & 7) << 3))

// ---------------- K0: fused transpose (64x64 tiles) + weight prep ----------------
__global__ __launch_bounds__(256) void prep_and_transpose(const float* __restrict__ x,
                                                          const float* __restrict__ w,
                                                          const float* __restrict__ pw,
                                                          unsigned short* __restrict__ xt,
                                                          unsigned short* __restrict__ WB,
                                                          unsigned short* __restrict__ PWs) {
  __shared__ float tile[64][65];   // 16,640 B
  int bid = blockIdx.x;
  int tid = threadIdx.x;
  if (bid < 1024) {
    int b = bid >> 8;
    int rest = bid & 255;
    int hw0 = (rest & 63) * 64;
    int c0 = (rest >> 6) * 64;
    {
      int col4 = (tid & 15) * 4;
      int crow = tid >> 4;
#pragma unroll
      for (int it = 0; it < 4; ++it) {
        int c = it * 16 + crow;
        float4 v = *(const float4*)&x[(size_t)(b * CIN + c0 + c) * HWS + hw0 + col4];
        tile[c][col4] = v.x;
        tile[c][col4 + 1] = v.y;
        tile[c][col4 + 2] = v.z;
        tile[c][col4 + 3] = v.w;
      }
    }
    __syncthreads();
    {
      int cc0 = (tid & 7) * 8;
      int rrow = tid >> 3;
#pragma unroll
      for (int it = 0; it < 2; ++it) {
        int r = it * 32 + rrow;
        uint4 o;
        o.x = (unsigned)f2bf(tile[cc0][r])     | ((unsigned)f2bf(tile[cc0 + 1][r]) << 16);
        o.y = (unsigned)f2bf(tile[cc0 + 2][r]) | ((unsigned)f2bf(tile[cc0 + 3][r]) << 16);
        o.z = (unsigned)f2bf(tile[cc0 + 4][r]) | ((unsigned)f2bf(tile[cc0 + 5][r]) << 16);
        o.w = (unsigned)f2bf(tile[cc0 + 6][r]) | ((unsigned)f2bf(tile[cc0 + 7][r]) << 16);
        *(uint4*)&xt[(size_t)(b * HWS + hw0 + r) * CIN + c0 + cc0] = o;
      }
    }
  } else {
    int idx = (bid - 1024) * 256 + tid;
    if (idx < KTOT * COUT) {
      // WB2[t][j][quad][row][8]: f = (((t*16+j)*4+quad)*16+row)*8+e
      int f = idx;
      int e = f & 7;
      int row = (f >> 3) & 15;
      int quad = (f >> 7) & 3;
      int j = (f >> 9) & 15;
      int t = f >> 13;                 // 0..71
      int kk = t * 32 + quad * 8 + e;
      int o = j * 16 + row;
      int k = kk >> 8, c = kk & 255;
      WB[f] = f2bf(w[o * KTOT + c * 9 + k]);
    } else {
      int f2 = idx - KTOT * COUT;   // < 2304*32
      int t_ = f2 & 7;
      int rest = f2 >> 3;
      int j = rest & 31;
      int kk = (rest >> 5) * 8 + t_;
      int k = kk >> 8, c = kk & 255;
      float v = (j < 27) ? pw[j * KTOT + c * 9 + k] : 0.0f;
      PWs[f2] = f2bf(v);
    }
  }
}

// ---------------- K3: fused offset-conv + index-prep + sample + GEMM ----------------
// (R27 structure; only change: setprio around MFMA clusters)
__device__ __forceinline__ void bilin8p(const uint4 c00, const uint4 c01,
                                        const uint4 c10, const uint4 c11,
                                        const float4 w4, unsigned short* dst) {
  uint4 o;
  float v0, v1;
  v0 = w4.x * bflo(c00.x) + w4.y * bflo(c01.x) + w4.z * bflo(c10.x) + w4.w * bflo(c11.x);
  v1 = w4.x * bfhi(c00.x) + w4.y * bfhi(c01.x) + w4.z * bfhi(c10.x) + w4.w * bfhi(c11.x);
  o.x = (unsigned)f2bf(v0) | ((unsigned)f2bf(v1) << 16);
  v0 = w4.x * bflo(c00.y) + w4.y * bflo(c01.y) + w4.z * bflo(c10.y) + w4.w * bflo(c11.y);
  v1 = w4.x * bfhi(c00.y) + w4.y * bfhi(c01.y) + w4.z * bfhi(c10.y) + w4.w * bfhi(c11.y);
  o.y = (unsigned)f2bf(v0) | ((unsigned)f2bf(v1) << 16);
  v0 = w4.x * bflo(c00.z) + w4.y * bflo(c01.z) + w4.z * bflo(c10.z) + w4.w * bflo(c11.z);
  v1 = w4.x * bfhi(c00.z) + w4.y * bfhi(c01.z) + w4.z * bfhi(c10.z) + w4.w * bfhi(c11.z);
  o.z = (unsigned)f2bf(v0) | ((unsigned)f2bf(v1) << 16);
  v0 = w4.x * bflo(c00.w) + w4.y * bflo(c01.w) + w4.z * bflo(c10.w) + w4.w * bflo(c11.w);
  v1 = w4.x * bfhi(c00.w) + w4.y * bfhi(c01.w) + w4.z * bfhi(c10.w) + w4.w * bfhi(c11.w);
  o.w = (unsigned)f2bf(v0) | ((unsigned)f2bf(v1) << 16);
  *(uint4*)dst = o;
}

#define MFMA16P(B0, B1, B2, B3)                                                          \
  acc[0][0] = __builtin_amdgcn_mfma_f32_16x16x32_bf16(afr0, B0, acc[0][0], 0, 0, 0);     \
  acc[0][1] = __builtin_amdgcn_mfma_f32_16x16x32_bf16(afr0, B1, acc[0][1], 0, 0, 0);     \
  acc[1][0] = __builtin_amdgcn_mfma_f32_16x16x32_bf16(afr1, B0, acc[1][0], 0, 0, 0);     \
  acc[1][1] = __builtin_amdgcn_mfma_f32_16x16x32_bf16(afr1, B1, acc[1][1], 0, 0, 0);     \
  acc[2][0] = __builtin_amdgcn_mfma_f32_16x16x32_bf16(afr2, B0, acc[2][0], 0, 0, 0);     \
  acc[2][1] = __builtin_amdgcn_mfma_f32_16x16x32_bf16(afr2, B1, acc[2][1], 0, 0, 0);     \
  acc[3][0] = __builtin_amdgcn_mfma_f32_16x16x32_bf16(afr3, B0, acc[3][0], 0, 0, 0);     \
  acc[3][1] = __builtin_amdgcn_mfma_f32_16x16x32_bf16(afr3, B1, acc[3][1], 0, 0, 0);     \
  acc[0][0] = __builtin_amdgcn_mfma_f32_16x16x32_bf16(afr4, B2, acc[0][0], 0, 0, 0);     \
  acc[0][1] = __builtin_amdgcn_mfma_f32_16x16x32_bf16(afr4, B3, acc[0][1], 0, 0, 0);     \
  acc[1][0] = __builtin_amdgcn_mfma_f32_16x16x32_bf16(afr5, B2, acc[1][0], 0, 0, 0);     \
  acc[1][1] = __builtin_amdgcn_mfma_f32_16x16x32_bf16(afr5, B3, acc[1][1], 0, 0, 0);     \
  acc[2][0] = __builtin_amdgcn_mfma_f32_16x16x32_bf16(afr6, B2, acc[2][0], 0, 0, 0);     \
  acc[2][1] = __builtin_amdgcn_mfma_f32_16x16x32_bf16(afr6, B3, acc[2][1], 0, 0, 0);     \
  acc[3][0] = __builtin_amdgcn_mfma_f32_16x16x32_bf16(afr7, B2, acc[3][0], 0, 0, 0);     \
  acc[3][1] = __builtin_amdgcn_mfma_f32_16x16x32_bf16(afr7, B3, acc[3][1], 0, 0, 0);

// Steady period P. GI* receive G(P+2 data); GC* hold G(P+1) (issued at P-1).
// BI* receive B(P+1); BC* hold B(P) (issued at P-1, oldest in flight).
#define FITER_P2(P, PAR, GI0, GI1, GI2, GI3, GC0, GC1, GC2, GC3,                         \
                 BC0, BC1, BC2, BC3, BI0, BI1, BI2, BI3)                                 \
  {                                                                                      \
    const unsigned short* btn = bpb + (size_t)(2 * ((P) + 1)) * 8192;                    \
    GLOAD16(BI0, btn);                                                                   \
    GLOAD16(BI1, btn + 512);                                                             \
    GLOAD16(BI2, btn + 8192);                                                            \
    GLOAD16(BI3, btn + 8192 + 512);                                                      \
    if ((((P) + 2) & 3) == 0) dI4 = Tbl[r][((P) + 2) >> 2][0];                           \
    int cb = ((2 * (P) + 4) & 7) * 32 + qo8;                                             \
    GLOAD16(GI0, xtb + dI4.x + cb);                                                      \
    GLOAD16(GI1, xtb + dI4.y + cb);                                                      \
    GLOAD16(GI2, xtb + dI4.z + cb);                                                      \
    GLOAD16(GI3, xtb + dI4.w + cb);                                                      \
    afr0 = *(const bf16x8*)&As[PAR][row][ASW(quad * 8, row)];                            \
    afr1 = *(const bf16x8*)&As[PAR][16 + row][ASW(quad * 8, row)];                       \
    afr2 = *(const bf16x8*)&As[PAR][32 + row][ASW(quad * 8, row)];                       \
    afr3 = *(const bf16x8*)&As[PAR][48 + row][ASW(quad * 8, row)];                       \
    afr4 = *(const bf16x8*)&As[PAR][row][ASW(32 + quad * 8, row)];                       \
    afr5 = *(const bf16x8*)&As[PAR][16 + row][ASW(32 + quad * 8, row)];                  \
    afr6 = *(const bf16x8*)&As[PAR][32 + row][ASW(32 + quad * 8, row)];                  \
    afr7 = *(const bf16x8*)&As[PAR][48 + row][ASW(32 + quad * 8, row)];                  \
    if ((((P) + 1) & 3) == 0) dW4 = *(float4*)&Tbl[r][((P) + 1) >> 2][1];                \
    WAITVM(12)                                                                           \
    __builtin_amdgcn_s_setprio(1);                                                       \
    MFMA16P(BC0, BC1, BC2, BC3)                                                          \
    __builtin_amdgcn_s_setprio(0);                                                       \
    WAITVM(8)                                                                            \
    bilin8p(GC0, GC1, GC2, GC3, dW4, &As[PAR ^ 1][r][ASW(qo8, r)]);                      \
    BARRIER_LGKM                                                                         \
  }

__global__ __launch_bounds__(512, 2) void fused_gemm(const unsigned short* __restrict__ xt,
                                                     const unsigned short* __restrict__ PWs,
                                                     const float* __restrict__ p_bias,
                                                     const unsigned short* __restrict__ WB,
                                                     const float* __restrict__ bias,
                                                     float* __restrict__ out) {
  __shared__ unsigned short As[2][64][64];   // 16,384 B, XOR-swizzled columns
  __shared__ int4 Tbl[64][9][2];             // 18,432 B [r][tap]{dI, dW}
  __shared__ float Ptl[8][64][32];           // 65,536 B offset-conv partials

  int tid = threadIdx.x;
  int lane = tid & 63, wv = tid >> 6;        // 8 waves
  int row = lane & 15, quad = lane >> 4;
  int mt = (blockIdx.x & 7) * 32 + (blockIdx.x >> 3);   // XCD-chunked swizzle
  int mb = mt * 64;
  int b = mb >> 12;
  int hw0 = mb & 4095;
  const unsigned short* xtb = xt + ((size_t)b << 20);

  // ---- (a) offset conv (ex-K1): wave wv covers k-tiles 9wv..9wv+8 ----
  {
    f32x4 aco[4][2] = {};
    for (int tt = 0; tt < 9; ++tt) {
      int t = wv * 9 + tt;
      int k = t >> 3, c0 = (t & 7) * 32;
      int dyk = k / 3 - 1, dxk = k % 3 - 1;
      const unsigned short* pb = PWs + (size_t)t * 1024 + (quad * 32 + row) * 8;
      bf16x8 ob0 = *(const bf16x8*)pb;           // j=0
      bf16x8 ob1 = *(const bf16x8*)(pb + 128);   // j=1
#pragma unroll
      for (int rs = 0; rs < 4; ++rs) {
        int hw = hw0 + rs * 16 + row;
        int h = hw >> 6, wq = hw & 63;
        int y = h + dyk, xx = wq + dxk;
        bf16x8 oa = {};
        if (((unsigned)y < 64u) && ((unsigned)xx < 64u))
          oa = *(const bf16x8*)(xtb + (size_t)(((y << 6) + xx) << 8) + c0 + quad * 8);
        aco[rs][0] = __builtin_amdgcn_mfma_f32_16x16x32_bf16(oa, ob0, aco[rs][0], 0, 0, 0);
        aco[rs][1] = __builtin_amdgcn_mfma_f32_16x16x32_bf16(oa, ob1, aco[rs][1], 0, 0, 0);
      }
    }
#pragma unroll
    for (int rs = 0; rs < 4; ++rs)
#pragma unroll
      for (int j = 0; j < 2; ++j)
#pragma unroll
        for (int e = 0; e < 4; ++e)
          Ptl[wv][rs * 16 + quad * 4 + e][j * 16 + row] = aco[rs][j][e];
  }
  __syncthreads();

  // ---- (b) reduce 8 waves' partials into Ptl[0] ----
  for (int i = tid; i < 2048; i += 512) {
    int lm = i >> 5, n = i & 31;
    float s = Ptl[0][lm][n];
#pragma unroll
    for (int w = 1; w < 8; ++w) s += Ptl[w][lm][n];
    Ptl[0][lm][n] = s;
  }
  __syncthreads();

  // ---- (c) index prep (ex-K2): 576 (row, tap) pairs over 512 threads ----
  for (int pr = tid; pr < 576; pr += 512) {
    int lm = pr / 9;
    int k = pr - lm * 9;
    int m = mb + lm;

    float dy = p_bias[2 * k] + Ptl[0][lm][2 * k];
    float dx = p_bias[2 * k + 1] + Ptl[0][lm][2 * k + 1];
    float mv = p_bias[18 + k] + Ptl[0][lm][18 + k];
    float mk = 1.0f / (1.0f + __expf(-mv));

    int hw = m & 4095, h = hw >> 6, ww = hw & 63;
    float py = (float)(h - 1 + k / 3) + dy;
    float px = (float)(ww - 1 + k % 3) + dx;
    float y0f = floorf(py), x0f = floorf(px);
    float ay = py - y0f, ax = px - x0f;
    int y0 = (int)y0f, x0 = (int)x0f;

    float w00 = (1.f - ay) * (1.f - ax) * mk;
    float w01 = (1.f - ay) * ax * mk;
    float w10 = ay * (1.f - ax) * mk;
    float w11 = ay * ax * mk;

    float vy0 = ((unsigned)y0 < 64u) ? 1.f : 0.f;
    float vy1 = ((unsigned)(y0 + 1) < 64u) ? 1.f : 0.f;
    float vx0 = ((unsigned)x0 < 64u) ? 1.f : 0.f;
    float vx1 = ((unsigned)(x0 + 1) < 64u) ? 1.f : 0.f;
    w00 *= vy0 * vx0; w01 *= vy0 * vx1; w10 *= vy1 * vx0; w11 *= vy1 * vx1;

    int yc0 = min(max(y0, 0), 63), yc1 = min(max(y0 + 1, 0), 63);
    int xc0 = min(max(x0, 0), 63), xc1 = min(max(x0 + 1, 0), 63);

    Tbl[lm][k][0] = make_int4((yc0 * 64 + xc0) * 256, (yc0 * 64 + xc1) * 256,
                              (yc1 * 64 + xc0) * 256, (yc1 * 64 + xc1) * 256);
    *(float4*)&Tbl[lm][k][1] = make_float4(w00, w01, w10, w11);
  }
  __syncthreads();   // full drain (vmcnt+lgkm) BEFORE any pinned loads

  int r = tid >> 3;         // sampler row 0..63 (8 threads/row)
  int qo8 = (tid & 7) * 8;  // sampler channel sub-block (8 ch, 16 B)

  int4 dI4 = Tbl[r][0][0];
  float4 dW4 = *(float4*)&Tbl[r][0][1];

  const unsigned short* bpb = WB + (size_t)(wv * 2) * 512 + quad * 128 + row * 8;

  f32x4 acc[4][2] = {};
  uint4 gA0, gA1, gA2, gA3;            // even-period gather set
  uint4 gB0, gB1, gB2, gB3;            // odd-period gather set
  bf16x8 bA0, bA1, bA2, bA3;           // even-period B set
  bf16x8 bB0, bB1, bB2, bB3;           // odd-period B set
  bf16x8 afr0, afr1, afr2, afr3, afr4, afr5, afr6, afr7;

  // ---- prologue: sample period 0 via compiler loads; pin B(0), G(1) ----
  {
    uint4 p00 = *(const uint4*)(xtb + dI4.x + qo8);
    uint4 p01 = *(const uint4*)(xtb + dI4.y + qo8);
    uint4 p10 = *(const uint4*)(xtb + dI4.z + qo8);
    uint4 p11 = *(const uint4*)(xtb + dI4.w + qo8);
    bilin8p(p00, p01, p10, p11, dW4, &As[0][r][ASW(qo8, r)]);
    // pinned issues, ORDER: B(0) x4 first (oldest), then G(1) x4
    GLOAD16(bA0, bpb);
    GLOAD16(bA1, bpb + 512);
    GLOAD16(bA2, bpb + 8192);
    GLOAD16(bA3, bpb + 8192 + 512);
    int cb1 = 64 + qo8;   // period 1 = tiles 2,3 (ch 64..127), tap 0
    GLOAD16(gA0, xtb + dI4.x + cb1);
    GLOAD16(gA1, xtb + dI4.y + cb1);
    GLOAD16(gA2, xtb + dI4.z + cb1);
    GLOAD16(gA3, xtb + dI4.w + cb1);
  }
  BARRIER_LGKM   // As[0] visible; 8 pinned loads in flight

  // ---- steady loop: periods 0..33 ----
#pragma unroll 1
  for (int p = 0; p < 34; p += 2) {
    FITER_P2(p,     0, gB0, gB1, gB2, gB3, gA0, gA1, gA2, gA3,
                       bA0, bA1, bA2, bA3, bB0, bB1, bB2, bB3)
    FITER_P2(p + 1, 1, gA0, gA1, gA2, gA3, gB0, gB1, gB2, gB3,
                       bB0, bB1, bB2, bB3, bA0, bA1, bA2, bA3)
  }

  // ---- peeled P=34 (PAR=0): BC=bA=B(34), GC=gA=G(35); issue B(35)->bB ----
  {
    const unsigned short* btn = bpb + (size_t)70 * 8192;
    GLOAD16(bB0, btn);
    GLOAD16(bB1, btn + 512);
    GLOAD16(bB2, btn + 8192);
    GLOAD16(bB3, btn + 8192 + 512);
    afr0 = *(const bf16x8*)&As[0][row][ASW(quad * 8, row)];
    afr1 = *(const bf16x8*)&As[0][16 + row][ASW(quad * 8, row)];
    afr2 = *(const bf16x8*)&As[0][32 + row][ASW(quad * 8, row)];
    afr3 = *(const bf16x8*)&As[0][48 + row][ASW(quad * 8, row)];
    afr4 = *(const bf16x8*)&As[0][row][ASW(32 + quad * 8, row)];
    afr5 = *(const bf16x8*)&As[0][16 + row][ASW(32 + quad * 8, row)];
    afr6 = *(const bf16x8*)&As[0][32 + row][ASW(32 + quad * 8, row)];
    afr7 = *(const bf16x8*)&As[0][48 + row][ASW(32 + quad * 8, row)];
    WAITVM(8)    // drains B(34)
    __builtin_amdgcn_s_setprio(1);
    MFMA16P(bA0, bA1, bA2, bA3)
    __builtin_amdgcn_s_setprio(0);
    WAITVM(4)    // drains G(35)
    bilin8p(gA0, gA1, gA2, gA3, dW4, &As[1][r][ASW(qo8, r)]);   // dW4 = tap 8
    BARRIER_LGKM
  }
  // ---- peeled P=35 (PAR=1): BC=bB=B(35); no bilin ----
  {
    afr0 = *(const bf16x8*)&As[1][row][ASW(quad * 8, row)];
    afr1 = *(const bf16x8*)&As[1][16 + row][ASW(quad * 8, row)];
    afr2 = *(const bf16x8*)&As[1][32 + row][ASW(quad * 8, row)];
    afr3 = *(const bf16x8*)&As[1][48 + row][ASW(quad * 8, row)];
    afr4 = *(const bf16x8*)&As[1][row][ASW(32 + quad * 8, row)];
    afr5 = *(const bf16x8*)&As[1][16 + row][ASW(32 + quad * 8, row)];
    afr6 = *(const bf16x8*)&As[1][32 + row][ASW(32 + quad * 8, row)];
    afr7 = *(const bf16x8*)&As[1][48 + row][ASW(32 + quad * 8, row)];
    WAITVM(0)
    __builtin_amdgcn_s_setprio(1);
    MFMA16P(bB0, bB1, bB2, bB3)
    __builtin_amdgcn_s_setprio(0);
  }

  // ---- epilogue: add bias, store NCHW ----
#pragma unroll
  for (int j = 0; j < 2; ++j) {
    int o = wv * 32 + j * 16 + row;
    float bo = bias[o];
#pragma unroll
    for (int i = 0; i < 4; ++i) {
      int hw = hw0 + i * 16 + quad * 4;
      float4 v;
      v.x = acc[i][j][0] + bo;
      v.y = acc[i][j][1] + bo;
      v.z = acc[i][j][2] + bo;
      v.w = acc[i][j][3] + bo;
      *(float4*)(out + (((size_t)(b * COUT + o)) << 12) + hw) = v;
    }
  }
}

// ---------------- launch ----------------
extern "C" void kernel_launch(void* const* d_in, const int* in_sizes, int n_in,
                              void* d_out, int out_size, void* d_ws, size_t ws_size,
                              hipStream_t stream) {
  const float* x        = (const float*)d_in[0];
  const float* weight   = (const float*)d_in[1];
  const float* bias     = (const float*)d_in[2];
  const float* p_weight = (const float*)d_in[3];
  const float* p_bias   = (const float*)d_in[4];
  float* out = (float*)d_out;
  char* ws = (char*)d_ws;

  // workspace layout (bytes); total ~9.7 MB
  const size_t OFF_XT   = 0;                          //  8,388,608  bf16 NHWC x
  const size_t OFF_WB   = OFF_XT + 8388608;           //  1,179,648  bf16 WB2
  const size_t OFF_PW   = OFF_WB + 1179648;           //    147,456  bf16

  unsigned short* xt    = (unsigned short*)(ws + OFF_XT);
  unsigned short* WB    = (unsigned short*)(ws + OFF_WB);
  unsigned short* PWs   = (unsigned short*)(ws + OFF_PW);

  prep_and_transpose<<<1024 + 2592, 256, 0, stream>>>(x, weight, p_weight, xt, WB, PWs);
  fused_gemm<<<256, 512, 0, stream>>>(xt, PWs, p_bias, WB, bias, out);
}